// Round 5
// baseline (260.020 us; speedup 1.0000x reference)
//
#include <hip/hip_runtime.h>

// LIF neuron forward: T=8 timesteps, x shape [T*B, C, H, W] = [256,128,32,32] f32.
// Recurrence per spatial element (independent across B,C,H,W):
//   mem = beta*mem + (1-beta)*x_t ; spike = (mem >= 0.3*Vth)*Vth ;
//   mem -= spike ; out_t = spike/0.05
//
// History:
//  R1: 1 float4/thread one-shot: 87 us, ~3.0 TB/s CU-side. Pipes idle.
//  R3: nt stores: 100 us. R4/R5: asm pins defeated/no effect.
//  R6: grid-stride x4, occupancy 62->31%: 94 us. Occupancy-insensitive.
//  R7: 2 contiguous cols/thread: 82 us. R8: K_COLS=8 interleaved, 32 KB
//      block bursts: 79.5 us (BEST). Burst length the only lever that moved.
//  R9/R10: C++-level whole-kernel read bursts (asm pins): VGPR stayed 40.
//  R11/R12: ISA-level burst (16 volatile global_load_dwordx4 + vmcnt(0)).
//      R12 carried freshness signatures: Kernel_Name and LDS_Block_Size
//      DID change -> binary fresh -- yet VGPR_Count still 40 and dur ~82.
//      VGPR=40 is liveness-impossible for the source as written (>=64 live
//      across the volatile wait, no spill traffic). Either (a) toolchain
//      still de-bursts (stores legally schedulable across no-mem-clobber
//      load asms; live-range games) -> reads latency-bound; or (b) bursts
//      happen, VGPR misreported -> MLP theory FALSIFIED and the R/W mix
//      itself caps at half copy BW. Counters cannot distinguish.
//  R13 (this): INSTRUMENTED ROUND. Three dispatches:
//      1) probe_read_r13: pure read of all 134 MB in R8's exact pattern,
//         sum-reduced (no DCE), 2 MB sink writes -> read-only ceiling.
//      2) probe_write_r13: pure write of all 134 MB, same pattern
//         -> write-only ceiling (expect ~6.5 TB/s like fillBuffer).
//      3) lif_fwd_r13 = exact R8 kernel, runs LAST (writes every output
//         byte -> correctness preserved; absmax must stay 0.0).
//      Decision rule: probe_read fast (>=4 TB/s) -> mix/structure is the
//      cost, go LDS-staged phase separation. probe_read slow (~1.7 TB/s)
//      -> read pattern latency-bound, fix access pattern. Score this
//      round is sacrificed (~+55 us) for the measurement.
//
// Bit-exactness notes (decisions flip 0<->20, zero flips allowed):
//  - beta = f32(exp(f32(-0.05))) = 0x1.E7078Cp-1 (correctly rounded; verified
//    absmax 0.0 in R1..R12).
//  - mem update uses __fmul_rn/__fadd_rn to forbid FMA contraction (numpy
//    evaluates beta*mem and (1-beta)*xt as separate rn-multiplies + rn-add).
//  - (1.0f - beta) exact; Vth clamp round-trips to 1.0f; vth/0.05f == 20.0f.

#define T_STEPS 8
#define S_ELEMS (32 * 128 * 32 * 32)   // per-timestep elements = 4,194,304
#define S4 (S_ELEMS / 4)               // float4 per timestep = 1,048,576
#define BLOCK 256
#define K_COLS 8                       // interleaved columns per thread
#define GRID (S4 / (BLOCK * K_COLS))   // 512 blocks = 2 blocks/CU

typedef float f32x4 __attribute__((ext_vector_type(4)));

// ---- Probe 1: pure read, R8 access pattern, sum-reduced. ----
__global__ __launch_bounds__(BLOCK) void probe_read_r13(
    const f32x4* __restrict__ x, float* __restrict__ sink) {
  const int base = blockIdx.x * (BLOCK * K_COLS) + threadIdx.x;
  float acc = 0.0f;
#pragma unroll
  for (int t = 0; t < T_STEPS; ++t) {
#pragma unroll
    for (int k = 0; k < K_COLS; ++k) {
      const f32x4 v = x[base + k * BLOCK + (size_t)t * S4];
      acc += v[0] + v[1] + v[2] + v[3];
    }
  }
  // 2 MB of sink writes (1.5% of probe traffic); overwritten by the real
  // kernel afterwards.
  sink[blockIdx.x * BLOCK + threadIdx.x] = acc;
}

// ---- Probe 2: pure write, R8 access pattern. ----
__global__ __launch_bounds__(BLOCK) void probe_write_r13(
    f32x4* __restrict__ out) {
  const int base = blockIdx.x * (BLOCK * K_COLS) + threadIdx.x;
  const f32x4 z = {0.0f, 0.0f, 0.0f, 0.0f};
#pragma unroll
  for (int t = 0; t < T_STEPS; ++t) {
#pragma unroll
    for (int k = 0; k < K_COLS; ++k) {
      out[base + k * BLOCK + (size_t)t * S4] = z;
    }
  }
}

// ---- Real kernel: exact R8 structure (best known, 79.5 us). ----
__global__ __launch_bounds__(BLOCK) void lif_fwd_r13(
    const f32x4* __restrict__ x, const float* __restrict__ vth_ptr,
    f32x4* __restrict__ out) {
  const int base = blockIdx.x * (BLOCK * K_COLS) + threadIdx.x;

  // Vth clamp (no-grad): relu(Vth - 5e-4) + 5e-4, all f32 rn. (scalar path)
  const float vth_raw = vth_ptr[0];
  const float vth = __fadd_rn(fmaxf(__fsub_rn(vth_raw, 0.0005f), 0.0f), 0.0005f);
  const float thr = __fmul_rn(0.3f, vth);      // ALPHA * Vth
  const float outval = __fdiv_rn(vth, 0.05f);  // Vth / DELTA_T (== 20.0f)

  const float beta = 0x1.E7078Cp-1f;        // f32(exp(f32(-0.05)))
  const float omb = __fsub_rn(1.0f, beta);  // exact

  float m[K_COLS * 4];
#pragma unroll
  for (int j = 0; j < K_COLS * 4; ++j) m[j] = 0.0f;

#pragma unroll
  for (int t = 0; t < T_STEPS; ++t) {
    const size_t p = (size_t)t * S4;

    // 8 back-to-back coalesced 1-KB loads: 32 KB contiguous block burst.
    f32x4 xv[K_COLS];
#pragma unroll
    for (int k = 0; k < K_COLS; ++k) xv[k] = x[base + k * BLOCK + p];

#pragma unroll
    for (int k = 0; k < K_COLS; ++k) {
      f32x4 o;
#pragma unroll
      for (int c = 0; c < 4; ++c) {
        const float mm =
            __fadd_rn(__fmul_rn(beta, m[k * 4 + c]), __fmul_rn(omb, xv[k][c]));
        const bool s = (mm >= thr);
        o[c] = s ? outval : 0.0f;
        m[k * 4 + c] = s ? __fsub_rn(mm, vth) : mm;
      }
      out[base + k * BLOCK + p] = o;
    }
  }
}

extern "C" void kernel_launch(void* const* d_in, const int* in_sizes, int n_in,
                              void* d_out, int out_size, void* d_ws,
                              size_t ws_size, hipStream_t stream) {
  const f32x4* x = (const f32x4*)d_in[0];
  const float* vth = (const float*)d_in[1];
  f32x4* out = (f32x4*)d_out;

  // Probes first (their scribbles on d_out are fully overwritten by the
  // real kernel below -- every output byte is written by lif_fwd_r13).
  probe_read_r13<<<GRID, BLOCK, 0, stream>>>(x, (float*)d_out);
  probe_write_r13<<<GRID, BLOCK, 0, stream>>>(out);
  lif_fwd_r13<<<GRID, BLOCK, 0, stream>>>(x, vth, out);
}

// Round 6
// 238.888 us; speedup vs baseline: 1.0885x; 1.0885x over previous
//
#include <hip/hip_runtime.h>

// LIF neuron forward: T=8 timesteps, x shape [T*B, C, H, W] = [256,128,32,32] f32.
// Recurrence per spatial element (independent across B,C,H,W):
//   mem = beta*mem + (1-beta)*x_t ; spike = (mem >= 0.3*Vth)*Vth ;
//   mem -= spike ; out_t = spike/0.05
//
// History:
//  R1: 87 us. R3 nt stores: 100 us. R4/R5 asm pins: defeated.
//  R6: occupancy-insensitive. R7: 82 us. R8: K_COLS=8, 32 KB block bursts:
//      79.5 us (BEST so far). Burst length the only lever that moved.
//  R9-R12: register-level whole-kernel read bursts (C++ pins, 16-operand
//      pin, volatile inline-asm loads): ALL defeated or ineffective; VGPR
//      stuck at 40 across all four (liveness-impossible for the source as
//      written) -- regalloc rewrites every register-level schedule.
//  R13 (instrumented): probe_read + probe_write combined ~25 us for 268 MB
//      (~10.7 TB/s aggregate) -- EACH STREAM ALONE IS FAST. Mixed kernel:
//      3.35 TB/s. m13 float4 copy (same 1:1 mix, fine interleave): 6.29
//      TB/s -- DRAM/fabric handles mixing fine. => the penalty is CU-side:
//      per-wave vmcnt FIFO mixing loads+stores; every load-wait drains the
//      previous stores. Regalloc defeats register-level fixes.
//  R14 (this): LDS-staged counted-vmcnt pipeline -- regalloc-proof.
//      global_load_lds has NO dest VGPRs (nothing to recycle); waits are
//      literal asm s_waitcnt vmcnt(N), never 0 (T3/T4 mechanism, m218:
//      counted-vs-drain0 = +38..73% on GEMM). Per wave: private 16 KB LDS
//      (2 bufs x 8 planes x 1 KB), no barriers (no cross-wave sharing).
//      Steady loop: issue 8 gll for it+1 -> vmcnt(16) retires ONLY L(it)
//      (S(it-1)+L(it+1) stay in flight) -> ds_read+compute+store from the
//      other buf. Every wave keeps 8 KB reads in flight through the whole
//      compute phase; 8 waves/CU = ~64 KB continuous read MLP (7x the
//      Little's-law need). Stores never gate loads.
//      FIFO wait-count proof (per wave, 8 ops per issue/store batch):
//        body(0): FIFO [L0][L1]          -> vmcnt(8)  retires L0.
//        body(i), 1<=i<=6: [S(i-2)?][Li][S(i-1)][L(i+1)] <=32
//                                        -> vmcnt(16) retires ..Li exactly.
//        body(7): [S5?][L7][S6] <=24     -> vmcnt(8)  retires ..L7.
//      If this lands ~80 us too, CU-side scheduling is exonerated and the
//      penalty is pattern-specific below the CUs -> roofline evidence.
//
// Bit-exactness notes (decisions flip 0<->20, zero flips allowed):
//  - beta = f32(exp(f32(-0.05))) = 0x1.E7078Cp-1 (correctly rounded; verified
//    absmax 0.0 in R1..R13). LDS round-trip is bit-preserving.
//  - mem update uses __fmul_rn/__fadd_rn to forbid FMA contraction (numpy
//    evaluates beta*mem and (1-beta)*xt as separate rn-multiplies + rn-add).
//  - (1.0f - beta) exact; Vth clamp round-trips to 1.0f; vth/0.05f == 20.0f.

#define T_STEPS 8
#define S_ELEMS (32 * 128 * 32 * 32)  // per-timestep elements = 4,194,304
#define S4 (S_ELEMS / 4)              // float4 per timestep = 1,048,576
#define BLOCK 256
#define W_PER_B 4                     // waves per block
#define ITERS 8
#define CHUNK4 256                    // block float4 per plane per iter
#define BSPAN (CHUNK4 * ITERS)        // 2048 float4 per plane per block
#define GRID (S4 / BSPAN)             // 512 blocks = 2/CU (LDS-limited), all resident

typedef float f32x4 __attribute__((ext_vector_type(4)));

// Counted waits; "memory" clobber pins all memory ops (gll / ds_read /
// stores) on their program-order side of the wait.
#define WAITV(n) asm volatile("s_waitcnt vmcnt(" #n ")" ::: "memory")

__device__ __forceinline__ void gload_lds16(const void* g, void* l) {
  __builtin_amdgcn_global_load_lds(
      (const __attribute__((address_space(1))) void*)g,
      (__attribute__((address_space(3))) void*)l, 16, 0, 0);
}

__global__ __launch_bounds__(BLOCK) void lif_fwd_r14(
    const f32x4* __restrict__ x, const float* __restrict__ vth_ptr,
    f32x4* __restrict__ out) {
  // 64 KB LDS: [wave 0..3][dbuf 0..1][plane 0..7][lane 0..63] of float4.
  __shared__ f32x4 lds4[4096];

  const int tid = threadIdx.x;
  const int lane = tid & 63;
  const int w = __builtin_amdgcn_readfirstlane(tid >> 6);  // wave-uniform

  // Vth clamp (no-grad): relu(Vth - 5e-4) + 5e-4, all f32 rn. (scalar path)
  const float vth_raw = vth_ptr[0];
  const float vth = __fadd_rn(fmaxf(__fsub_rn(vth_raw, 0.0005f), 0.0f), 0.0005f);
  const float thr = __fmul_rn(0.3f, vth);      // ALPHA * Vth
  const float outval = __fdiv_rn(vth, 0.05f);  // Vth / DELTA_T (== 20.0f)

  const float beta = 0x1.E7078Cp-1f;        // f32(exp(f32(-0.05)))
  const float omb = __fsub_rn(1.0f, beta);  // exact

  const int bbase = blockIdx.x * BSPAN;  // block's float4 base within a plane

  // Per-wave private LDS buffers (wave-uniform pointers; HW adds lane*16B).
  f32x4* const lw[2] = {&lds4[w * 1024], &lds4[w * 1024 + 512]};

  // Issue 8 async global->LDS loads (one per plane) for chunk `it`.
  auto issue8 = [&](int it, f32x4* lbuf) {
    const f32x4* gp = x + (size_t)(bbase + it * CHUNK4 + w * 64 + lane);
#pragma unroll
    for (int t = 0; t < T_STEPS; ++t) {
      gload_lds16(gp + (size_t)t * S4, lbuf + t * 64);
    }
  };

  // Consume chunk `it` from LDS: full t-recurrence for this thread's
  // float4 column, 8 coalesced 1-KB stores.
  auto compute8 = [&](int it, const f32x4* lbuf) {
    const size_t gbase = (size_t)(bbase + it * CHUNK4 + w * 64 + lane);
    float m0 = 0.0f, m1 = 0.0f, m2 = 0.0f, m3 = 0.0f;
#pragma unroll
    for (int t = 0; t < T_STEPS; ++t) {
      const f32x4 xv = lbuf[t * 64 + lane];
      f32x4 o;
      {
        const float mm = __fadd_rn(__fmul_rn(beta, m0), __fmul_rn(omb, xv[0]));
        const bool s = (mm >= thr);
        o[0] = s ? outval : 0.0f;
        m0 = s ? __fsub_rn(mm, vth) : mm;
      }
      {
        const float mm = __fadd_rn(__fmul_rn(beta, m1), __fmul_rn(omb, xv[1]));
        const bool s = (mm >= thr);
        o[1] = s ? outval : 0.0f;
        m1 = s ? __fsub_rn(mm, vth) : mm;
      }
      {
        const float mm = __fadd_rn(__fmul_rn(beta, m2), __fmul_rn(omb, xv[2]));
        const bool s = (mm >= thr);
        o[2] = s ? outval : 0.0f;
        m2 = s ? __fsub_rn(mm, vth) : mm;
      }
      {
        const float mm = __fadd_rn(__fmul_rn(beta, m3), __fmul_rn(omb, xv[3]));
        const bool s = (mm >= thr);
        o[3] = s ? outval : 0.0f;
        m3 = s ? __fsub_rn(mm, vth) : mm;
      }
      out[gbase + (size_t)t * S4] = o;
    }
  };

  // Software pipeline, fully unrolled so every vmcnt is a literal.
  issue8(0, lw[0]);
  issue8(1, lw[1]); WAITV(8);  compute8(0, lw[0]);
  issue8(2, lw[0]); WAITV(16); compute8(1, lw[1]);
  issue8(3, lw[1]); WAITV(16); compute8(2, lw[0]);
  issue8(4, lw[0]); WAITV(16); compute8(3, lw[1]);
  issue8(5, lw[1]); WAITV(16); compute8(4, lw[0]);
  issue8(6, lw[0]); WAITV(16); compute8(5, lw[1]);
  issue8(7, lw[1]); WAITV(16); compute8(6, lw[0]);
                    WAITV(8);  compute8(7, lw[1]);
}

extern "C" void kernel_launch(void* const* d_in, const int* in_sizes, int n_in,
                              void* d_out, int out_size, void* d_ws,
                              size_t ws_size, hipStream_t stream) {
  const f32x4* x = (const f32x4*)d_in[0];
  const float* vth = (const float*)d_in[1];
  f32x4* out = (f32x4*)d_out;
  lif_fwd_r14<<<GRID, BLOCK, 0, stream>>>(x, vth, out);
}